// Round 1
// baseline (24.509 us; speedup 1.0000x reference)
//
#include <hip/hip_runtime.h>

// out = max over 2x2 windows (stride 2) of x: the reference's relu algebra
// collapses to max(a,b,c,d) per window.
// x: (32, 64, 112, 112) f32  ->  out: (32, 64, 56, 56) f32
//
// Each thread computes one output float4 (4 output pixels in one output row):
// reads 2x float4 from input row 2*oh and 2x float4 from row 2*oh+1.
// All loads/stores 16B-aligned and coalesced.

__global__ __launch_bounds__(256) void maxpool2x2_kernel(const float* __restrict__ x,
                                                         float* __restrict__ out,
                                                         int n_v4) {
    int t = blockIdx.x * blockDim.x + threadIdx.x;
    if (t >= n_v4) return;

    const int OW4 = 14;                 // 56 output cols / 4 per float4
    int row = t / OW4;                  // img*56 + oh
    int q   = t - row * OW4;            // which float4 within the output row
    int img = row / 56;                 // img = n*64 + c
    int oh  = row - img * 56;

    const float* base = x + (size_t)img * (112 * 112) + (size_t)(2 * oh) * 112 + q * 8;

    float4 r0a = *reinterpret_cast<const float4*>(base);
    float4 r0b = *reinterpret_cast<const float4*>(base + 4);
    float4 r1a = *reinterpret_cast<const float4*>(base + 112);
    float4 r1b = *reinterpret_cast<const float4*>(base + 116);

    float4 o;
    o.x = fmaxf(fmaxf(r0a.x, r0a.y), fmaxf(r1a.x, r1a.y));
    o.y = fmaxf(fmaxf(r0a.z, r0a.w), fmaxf(r1a.z, r1a.w));
    o.z = fmaxf(fmaxf(r0b.x, r0b.y), fmaxf(r1b.x, r1b.y));
    o.w = fmaxf(fmaxf(r0b.z, r0b.w), fmaxf(r1b.z, r1b.w));

    *reinterpret_cast<float4*>(out + (size_t)t * 4) = o;
}

extern "C" void kernel_launch(void* const* d_in, const int* in_sizes, int n_in,
                              void* d_out, int out_size, void* d_ws, size_t ws_size,
                              hipStream_t stream) {
    const float* x = (const float*)d_in[0];
    float* out = (float*)d_out;

    // out_size = 32*64*56*56 = 6,422,528 ; n_v4 = out_size/4 = 1,605,632
    int n_v4 = out_size / 4;
    int block = 256;
    int grid = (n_v4 + block - 1) / block;   // 6272

    maxpool2x2_kernel<<<grid, block, 0, stream>>>(x, out, n_v4);
}